// Round 7
// baseline (528.377 us; speedup 1.0000x reference)
//
#include <hip/hip_runtime.h>

#define B_ 4
#define NH_ 32
#define SQ_ 512
#define HD_ 128
#define MLEN_ 3584
#define KT_ 4096           // MLEN_ + SQ_
#define QB_ 128
#define KB_ 64
#define NTILE_ 64          // KT_ / KB_
#define MEMTILES_ 56       // MLEN_ / KB_

typedef float f32x4 __attribute__((ext_vector_type(4)));
typedef short s16x8 __attribute__((ext_vector_type(8)));

__device__ __forceinline__ f32x4 MFMA16(s16x8 a, s16x8 b, f32x4 c) {
    return __builtin_amdgcn_mfma_f32_16x16x32_bf16(a, b, c, 0, 0, 0);
}

// Barrier that does NOT drain vmcnt (LDS correctness only needs lgkmcnt).
// The "memory" clobber also pins our prefetch issues on their side of it.
__device__ __forceinline__ void wg_barrier() {
    asm volatile("s_waitcnt lgkmcnt(0)\n\ts_barrier" ::: "memory");
}

__device__ __forceinline__ s16x8 cvt8(float4 a, float4 b) {
    union { s16x8 v; __bf16 h[8]; } u;
    u.h[0] = (__bf16)a.x; u.h[1] = (__bf16)a.y;
    u.h[2] = (__bf16)a.z; u.h[3] = (__bf16)a.w;
    u.h[4] = (__bf16)b.x; u.h[5] = (__bf16)b.y;
    u.h[6] = (__bf16)b.z; u.h[7] = (__bf16)b.w;
    return u.v;
}

// 8 waves x 16 q-rows; double-buffered K/V (64KB LDS) -> 2 blocks/CU;
// one lgkm-only barrier per tile; reg-prefetch one tile ahead.
__launch_bounds__(512, 4)
__global__ void attn_kernel(const float* __restrict__ q, const float* __restrict__ k,
                            const float* __restrict__ v, const float* __restrict__ mask,
                            const float* __restrict__ mem, float* __restrict__ ctx)
{
    __shared__ __bf16 Klds[2][KB_ * HD_];     // 2 x 16 KB, swizzled rows
    __shared__ __bf16 Vt[2][HD_ * KB_];       // 2 x 16 KB, transposed + swizzled

    const int tid  = threadIdx.x;
    const int lane = tid & 63;
    const int w    = tid >> 6;                // 0..7
    const int l15  = lane & 15;
    const int l4   = lane >> 4;               // 0..3
    const int xv   = (lane & 7) << 4;

    const int qt   = blockIdx.x >> 7;
    const int pair = blockIdx.x & 127;
    const int b    = pair >> 5;
    const int h    = pair & 31;
    const int q0   = qt * QB_;

    // ---- Q fragments (B-operand; lane l15 = q-row, l4*8+j = d), scale folded ----
    const float scale = 0.088388347648318447f;   // 1/sqrt(128)
    s16x8 qf[4];
    {
        const float* qbase = q + (((size_t)(b * NH_ + h)) * SQ_ + q0 + w * 16 + l15) * HD_;
        #pragma unroll
        for (int kc = 0; kc < 4; ++kc) {
            const float* p = qbase + kc * 32 + l4 * 8;
            float4 a = *(const float4*)p;
            float4 c = *(const float4*)(p + 4);
            a.x *= scale; a.y *= scale; a.z *= scale; a.w *= scale;
            c.x *= scale; c.y *= scale; c.z *= scale; c.w *= scale;
            qf[kc] = cvt8(a, c);
        }
    }

    // O accumulator: acc[nn] rows q = l4*4+r, cols hd = nn*16 + l15
    f32x4 acc[8];
    #pragma unroll
    for (int n = 0; n < 8; ++n) acc[n] = (f32x4){0.f, 0.f, 0.f, 0.f};

    float mrun = -3.0e38f, lrun = 0.f;        // per-lane stats for q = w*16 + l15

    const float* maskrow = mask + ((size_t)b * SQ_ + q0 + w * 16 + l15) * KT_;

    const int krow = tid >> 4,  kcg  = tid & 15;   // K stage unit (unit1 = +32 rows)
    const int vhd  = tid & 127, vkvb = tid >> 7;   // V stage unit (unit1 = +4 kvb)

    // ---- prefetch registers (one tile ahead) ----
    float4 kpa[2], kpb[2];
    float  vpre[2][8];
    f32x4  mk[4];                                  // mask for the CURRENT tile

    auto issueKV = [&](int t) {
        const int kv0 = t * KB_;
        const float *srcK, *srcV;
        int rstride;
        if (t < MEMTILES_) {
            const float* mrow = mem + ((size_t)b * MLEN_ + kv0) * (2 * NH_ * HD_) + h * HD_;
            srcK = mrow;
            srcV = mrow + NH_ * HD_;
            rstride = 2 * NH_ * HD_;
        } else {
            size_t off = (((size_t)b * NH_ + h) * SQ_ + (kv0 - MLEN_)) * HD_;
            srcK = k + off;
            srcV = v + off;
            rstride = HD_;
        }
        #pragma unroll
        for (int it = 0; it < 2; ++it) {
            const float* p = srcK + (size_t)(krow + it * 32) * rstride + kcg * 8;
            kpa[it] = *(const float4*)p;
            kpb[it] = *(const float4*)(p + 4);
        }
        #pragma unroll
        for (int it = 0; it < 2; ++it) {
            const float* p = srcV + (size_t)((vkvb + it * 4) * 8) * rstride + vhd;
            #pragma unroll
            for (int j = 0; j < 8; ++j) vpre[it][j] = p[(size_t)j * rstride];
        }
    };
    auto writeKV = [&](int buf) {
        #pragma unroll
        for (int it = 0; it < 2; ++it) {
            int row = krow + it * 32;
            s16x8 vv = cvt8(float4{kpa[it].x, kpa[it].y, kpa[it].z, kpa[it].w},
                            float4{kpb[it].x, kpb[it].y, kpb[it].z, kpb[it].w});
            int byte = row * 256 + ((kcg * 16) ^ ((row & 7) << 4));
            *(s16x8*)((char*)Klds[buf] + byte) = vv;
        }
        #pragma unroll
        for (int it = 0; it < 2; ++it) {
            int kvb = vkvb + it * 4;
            union { s16x8 v; __bf16 hh[8]; } u;
            #pragma unroll
            for (int j = 0; j < 8; ++j) u.hh[j] = (__bf16)vpre[it][j];
            int byte = vhd * 128 + ((kvb * 16) ^ ((vhd & 7) << 4));
            *(s16x8*)((char*)Vt[buf] + byte) = u.v;
        }
    };
    auto loadmask = [&](int t) {
        const int kv0 = t * KB_;
        #pragma unroll
        for (int mt = 0; mt < 4; ++mt)
            mk[mt] = *(const f32x4*)(maskrow + kv0 + mt * 16 + l4 * 4);
    };

    // ---- prologue: stage tile 0; put mask(0) then KV(1) in flight ----
    issueKV(0);
    writeKV(0);
    loadmask(0);      // issued BEFORE KV(1) -> retires before it (in-order)
    issueKV(1);
    wg_barrier();

    for (int t = 0; t < NTILE_; ++t) {
        const int cur = t & 1;

        // ---- S^T = K @ Q^T : st[mt] rows kv = mt*16 + l4*4 + r, cols q = l15 ----
        f32x4 st[4];
        #pragma unroll
        for (int mt = 0; mt < 4; ++mt) st[mt] = (f32x4){0.f, 0.f, 0.f, 0.f};
        #pragma unroll
        for (int mt = 0; mt < 4; ++mt) {
            #pragma unroll
            for (int kc = 0; kc < 4; ++kc) {
                s16x8 kf = *(const s16x8*)((const char*)Klds[cur] +
                            (mt * 16 + l15) * 256 + (((kc * 4 + l4) * 16) ^ xv));
                st[mt] = MFMA16(kf, qf[kc], st[mt]);
            }
        }

        // ---- mask apply (mask(t) was issued before KV(t+1): waits only on itself) ----
        #pragma unroll
        for (int mt = 0; mt < 4; ++mt)
            #pragma unroll
            for (int r = 0; r < 4; ++r)
                st[mt][r] = fmaf(mk[mt][r], st[mt][r] + 10000.f, -10000.f);

        // ---- in-register softmax over kv ----
        float x0 = fmaxf(fmaxf(st[0][0], st[0][1]), fmaxf(st[0][2], st[0][3]));
        float x1 = fmaxf(fmaxf(st[1][0], st[1][1]), fmaxf(st[1][2], st[1][3]));
        float x2 = fmaxf(fmaxf(st[2][0], st[2][1]), fmaxf(st[2][2], st[2][3]));
        float x3 = fmaxf(fmaxf(st[3][0], st[3][1]), fmaxf(st[3][2], st[3][3]));
        float rm = fmaxf(fmaxf(x0, x1), fmaxf(x2, x3));
        rm = fmaxf(rm, __shfl_xor(rm, 16));
        rm = fmaxf(rm, __shfl_xor(rm, 32));

        if (!__all(rm <= mrun + 8.f)) {       // defer-max
            float nm = fmaxf(mrun, rm);
            float al = __expf(mrun - nm);
            mrun = nm;
            lrun *= al;
            float alr0 = __shfl(al, l4 * 4 + 0);
            float alr1 = __shfl(al, l4 * 4 + 1);
            float alr2 = __shfl(al, l4 * 4 + 2);
            float alr3 = __shfl(al, l4 * 4 + 3);
            #pragma unroll
            for (int nn = 0; nn < 8; ++nn) {
                acc[nn][0] *= alr0; acc[nn][1] *= alr1;
                acc[nn][2] *= alr2; acc[nn][3] *= alr3;
            }
        }

        float rs = 0.f;
        #pragma unroll
        for (int mt = 0; mt < 4; ++mt) {
            #pragma unroll
            for (int r = 0; r < 4; ++r) {
                float pe = __expf(st[mt][r] - mrun);
                st[mt][r] = pe;
                rs += pe;
            }
        }
        rs += __shfl_xor(rs, 16);
        rs += __shfl_xor(rs, 32);
        lrun += rs;

        // ---- pack P^T to bf16 ----
        union PK { int d[2]; __bf16 hh[4]; };
        PK pk0, pk1, pk2, pk3;
        pk0.hh[0]=(__bf16)st[0][0]; pk0.hh[1]=(__bf16)st[0][1]; pk0.hh[2]=(__bf16)st[0][2]; pk0.hh[3]=(__bf16)st[0][3];
        pk1.hh[0]=(__bf16)st[1][0]; pk1.hh[1]=(__bf16)st[1][1]; pk1.hh[2]=(__bf16)st[1][2]; pk1.hh[3]=(__bf16)st[1][3];
        pk2.hh[0]=(__bf16)st[2][0]; pk2.hh[1]=(__bf16)st[2][1]; pk2.hh[2]=(__bf16)st[2][2]; pk2.hh[3]=(__bf16)st[2][3];
        pk3.hh[0]=(__bf16)st[3][0]; pk3.hh[1]=(__bf16)st[3][1]; pk3.hh[2]=(__bf16)st[3][2]; pk3.hh[3]=(__bf16)st[3][3];

        // ---- assemble PV A-fragments via shuffles ----
        const int srcA = (l4 & 1) * 32 + l15;
        const int srcB = srcA + 16;
        const int sel  = l4 >> 1;
        s16x8 pa[2];
        {
            union { int d[4]; s16x8 v; } ua;
            int a00 = __shfl(pk0.d[0], srcA), a10 = __shfl(pk1.d[0], srcA);
            int a01 = __shfl(pk0.d[1], srcA), a11 = __shfl(pk1.d[1], srcA);
            int b00 = __shfl(pk0.d[0], srcB), b10 = __shfl(pk1.d[0], srcB);
            int b01 = __shfl(pk0.d[1], srcB), b11 = __shfl(pk1.d[1], srcB);
            ua.d[0] = sel ? a10 : a00; ua.d[1] = sel ? a11 : a01;
            ua.d[2] = sel ? b10 : b00; ua.d[3] = sel ? b11 : b01;
            pa[0] = ua.v;
        }
        {
            union { int d[4]; s16x8 v; } ua;
            int a00 = __shfl(pk2.d[0], srcA), a10 = __shfl(pk3.d[0], srcA);
            int a01 = __shfl(pk2.d[1], srcA), a11 = __shfl(pk3.d[1], srcA);
            int b00 = __shfl(pk2.d[0], srcB), b10 = __shfl(pk3.d[0], srcB);
            int b01 = __shfl(pk2.d[1], srcB), b11 = __shfl(pk3.d[1], srcB);
            ua.d[0] = sel ? a10 : a00; ua.d[1] = sel ? a11 : a01;
            ua.d[2] = sel ? b10 : b00; ua.d[3] = sel ? b11 : b01;
            pa[1] = ua.v;
        }

        // ---- O += P @ V ----
        #pragma unroll
        for (int nn = 0; nn < 8; ++nn) {
            s16x8 vf0 = *(const s16x8*)((const char*)Vt[cur] +
                          (nn * 16 + l15) * 128 + ((l4 * 16) ^ xv));
            s16x8 vf1 = *(const s16x8*)((const char*)Vt[cur] +
                          (nn * 16 + l15) * 128 + ((64 + l4 * 16) ^ xv));
            acc[nn] = MFMA16(pa[0], vf0, acc[nn]);
            acc[nn] = MFMA16(pa[1], vf1, acc[nn]);
        }

        // ---- stage tile t+1 into the other buffer; refill prefetches ----
        if (t + 1 < NTILE_) {
            writeKV(cur ^ 1);          // vmcnt waits land here (a full tile of cover)
            loadmask(t + 1);           // issue mask FIRST (retires before KV(t+2))
            if (t + 2 < NTILE_) issueKV(t + 2);
        }
        wg_barrier();                  // one barrier per tile; vmcnt NOT drained
    }

    // ---- epilogue ----
    float lr0 = __shfl(lrun, l4 * 4 + 0);
    float lr1 = __shfl(lrun, l4 * 4 + 1);
    float lr2 = __shfl(lrun, l4 * 4 + 2);
    float lr3 = __shfl(lrun, l4 * 4 + 3);
    float inv0 = 1.f / lr0, inv1 = 1.f / lr1, inv2 = 1.f / lr2, inv3 = 1.f / lr3;
    float* obase = ctx + (((size_t)(b * NH_ + h)) * SQ_ + q0 + w * 16 + l4 * 4) * HD_ + l15;
    #pragma unroll
    for (int nn = 0; nn < 8; ++nn) {
        obase[(size_t)0 * HD_ + nn * 16] = acc[nn][0] * inv0;
        obase[(size_t)1 * HD_ + nn * 16] = acc[nn][1] * inv1;
        obase[(size_t)2 * HD_ + nn * 16] = acc[nn][2] * inv2;
        obase[(size_t)3 * HD_ + nn * 16] = acc[nn][3] * inv3;
    }
}

// cache_kv: out[b][s][part][h][d] = (part ? v : k)[b][h][s][d]
__global__ void cachekv_kernel(const float* __restrict__ k, const float* __restrict__ v,
                               float* __restrict__ out)
{
    size_t i = ((size_t)blockIdx.x * 256 + threadIdx.x) * 4;
    unsigned f = (unsigned)i;
    unsigned d    = f & 127;
    unsigned hh   = (f >> 7) & 31;
    unsigned part = (f >> 12) & 1;
    unsigned s    = (f >> 13) & 511;
    unsigned bb   = f >> 22;
    const float* src = (part ? v : k) + (((size_t)(bb * 32u + hh)) * 512u + s) * 128u + d;
    *(float4*)(out + i) = *(const float4*)src;
}

extern "C" void kernel_launch(void* const* d_in, const int* in_sizes, int n_in,
                              void* d_out, int out_size, void* d_ws, size_t ws_size,
                              hipStream_t stream) {
    const float* q    = (const float*)d_in[0];
    const float* k    = (const float*)d_in[1];
    const float* v    = (const float*)d_in[2];
    const float* mask = (const float*)d_in[3];
    const float* mem  = (const float*)d_in[4];
    float* out = (float*)d_out;

    attn_kernel<<<dim3(B_ * NH_ * (SQ_ / QB_)), dim3(512), 0, stream>>>(q, k, v, mask, mem, out);

    const int ctx_elems = B_ * NH_ * SQ_ * HD_;                 // 8388608
    const int ckv_elems = B_ * SQ_ * 2 * NH_ * HD_;             // 16777216
    cachekv_kernel<<<dim3(ckv_elems / 4 / 256), dim3(256), 0, stream>>>(k, v, out + ctx_elems);
    (void)in_sizes; (void)n_in; (void)out_size; (void)d_ws; (void)ws_size;
}

// Round 8
// 346.914 us; speedup vs baseline: 1.5231x; 1.5231x over previous
//
#include <hip/hip_runtime.h>

#define B_ 4
#define NH_ 32
#define SQ_ 512
#define HD_ 128
#define MLEN_ 3584
#define KT_ 4096           // MLEN_ + SQ_
#define QB_ 128
#define KB_ 64
#define NTILE_ 64          // KT_ / KB_
#define MEMTILES_ 56       // MLEN_ / KB_

typedef float f32x4 __attribute__((ext_vector_type(4)));
typedef short s16x8 __attribute__((ext_vector_type(8)));

__device__ __forceinline__ f32x4 MFMA16(s16x8 a, s16x8 b, f32x4 c) {
    return __builtin_amdgcn_mfma_f32_16x16x32_bf16(a, b, c, 0, 0, 0);
}

__device__ __forceinline__ s16x8 cvt8(float4 a, float4 b) {
    union { s16x8 v; __bf16 h[8]; } u;
    u.h[0] = (__bf16)a.x; u.h[1] = (__bf16)a.y;
    u.h[2] = (__bf16)a.z; u.h[3] = (__bf16)a.w;
    u.h[4] = (__bf16)b.x; u.h[5] = (__bf16)b.y;
    u.h[6] = (__bf16)b.z; u.h[7] = (__bf16)b.w;
    return u.v;
}

// 8 waves x 16 q-rows; double-buffered K/V (64 KB) -> 2 blocks/CU.
// One __syncthreads per tile; stage-loads(t+1) issued before compute(t),
// consumed by stage-writes after compute -> compiler sinks vmcnt waits.
__launch_bounds__(512, 4)
__global__ void attn_kernel(const float* __restrict__ q, const float* __restrict__ k,
                            const float* __restrict__ v, const float* __restrict__ mask,
                            const float* __restrict__ mem, float* __restrict__ ctx)
{
    __shared__ __bf16 Klds[2][KB_ * HD_];     // 2 x 16 KB, swizzled rows
    __shared__ __bf16 Vt[2][HD_ * KB_];       // 2 x 16 KB, transposed + swizzled

    const int tid  = threadIdx.x;
    const int lane = tid & 63;
    const int w    = tid >> 6;                // 0..7
    const int l15  = lane & 15;
    const int l4   = lane >> 4;               // 0..3
    const int xv   = (lane & 7) << 4;

    const int qt   = blockIdx.x >> 7;
    const int pair = blockIdx.x & 127;
    const int b    = pair >> 5;
    const int h    = pair & 31;
    const int q0   = qt * QB_;

    // ---- Q fragments (B-operand; lane l15 = q-row, l4*8+j = d), scale folded ----
    const float scale = 0.088388347648318447f;   // 1/sqrt(128)
    s16x8 qf[4];
    {
        const float* qbase = q + (((size_t)(b * NH_ + h)) * SQ_ + q0 + w * 16 + l15) * HD_;
        #pragma unroll
        for (int kc = 0; kc < 4; ++kc) {
            const float* p = qbase + kc * 32 + l4 * 8;
            float4 a = *(const float4*)p;
            float4 c = *(const float4*)(p + 4);
            a.x *= scale; a.y *= scale; a.z *= scale; a.w *= scale;
            c.x *= scale; c.y *= scale; c.z *= scale; c.w *= scale;
            qf[kc] = cvt8(a, c);
        }
    }

    f32x4 acc[8];
    #pragma unroll
    for (int n = 0; n < 8; ++n) acc[n] = (f32x4){0.f, 0.f, 0.f, 0.f};

    float mrun = -3.0e38f, lrun = 0.f;        // per-lane stats for q = w*16 + l15

    const float* maskrow = mask + ((size_t)b * SQ_ + q0 + w * 16 + l15) * KT_;

    const int krow = tid >> 4,  kcg  = tid & 15;   // K stage unit (unit1 = +32 rows)
    const int vhd  = tid & 127, vkvb = tid >> 7;   // V stage unit (unit1 = +4 kvb)

    // ---- prologue: stage tile 0 into buf 0 ----
    {
        const float* mrow = mem + ((size_t)b * MLEN_) * (2 * NH_ * HD_) + h * HD_;
        const float* srcK = mrow;
        const float* srcV = mrow + NH_ * HD_;
        const int rstride = 2 * NH_ * HD_;
        #pragma unroll
        for (int it = 0; it < 2; ++it) {
            int row = krow + it * 32;
            const float* p = srcK + (size_t)row * rstride + kcg * 8;
            float4 a = *(const float4*)p;
            float4 c = *(const float4*)(p + 4);
            int byte = row * 256 + ((kcg * 16) ^ ((row & 7) << 4));
            *(s16x8*)((char*)Klds[0] + byte) = cvt8(a, c);
        }
        #pragma unroll
        for (int it = 0; it < 2; ++it) {
            int kvb = vkvb + it * 4;
            const float* p = srcV + (size_t)(kvb * 8) * rstride + vhd;
            union { s16x8 v; __bf16 hh[8]; } u;
            #pragma unroll
            for (int j = 0; j < 8; ++j) u.hh[j] = (__bf16)p[(size_t)j * rstride];
            int byte = vhd * 128 + ((kvb * 16) ^ ((vhd & 7) << 4));
            *(s16x8*)((char*)Vt[0] + byte) = u.v;
        }
    }
    __syncthreads();

    for (int t = 0; t < NTILE_; ++t) {
        const int cur = t & 1;
        const int kv0 = t * KB_;
        const int tn  = (t + 1 < NTILE_) ? (t + 1) : (NTILE_ - 1);  // clamp (uniform)

        // ---- mask loads for tile t: issued FIRST so their vmcnt wait
        //      does not cover the stage loads below ----
        f32x4 mk[4];
        #pragma unroll
        for (int mt = 0; mt < 4; ++mt)
            mk[mt] = *(const f32x4*)(maskrow + kv0 + mt * 16 + l4 * 4);

        // ---- stage LOADS for tile tn (consumed only after compute) ----
        const float *srcK, *srcV;
        int rstride;
        {
            const int nkv0 = tn * KB_;
            if (tn < MEMTILES_) {
                const float* mrow = mem + ((size_t)b * MLEN_ + nkv0) * (2 * NH_ * HD_) + h * HD_;
                srcK = mrow;
                srcV = mrow + NH_ * HD_;
                rstride = 2 * NH_ * HD_;
            } else {
                size_t off = (((size_t)b * NH_ + h) * SQ_ + (nkv0 - MLEN_)) * HD_;
                srcK = k + off;
                srcV = v + off;
                rstride = HD_;
            }
        }
        float4 ka0, kb0, ka1, kb1;
        {
            const float* p0 = srcK + (size_t)krow * rstride + kcg * 8;
            ka0 = *(const float4*)p0;
            kb0 = *(const float4*)(p0 + 4);
            const float* p1 = srcK + (size_t)(krow + 32) * rstride + kcg * 8;
            ka1 = *(const float4*)p1;
            kb1 = *(const float4*)(p1 + 4);
        }
        float vp0[8], vp1[8];
        {
            const float* p0 = srcV + (size_t)(vkvb * 8) * rstride + vhd;
            #pragma unroll
            for (int j = 0; j < 8; ++j) vp0[j] = p0[(size_t)j * rstride];
            const float* p1 = srcV + (size_t)((vkvb + 4) * 8) * rstride + vhd;
            #pragma unroll
            for (int j = 0; j < 8; ++j) vp1[j] = p1[(size_t)j * rstride];
        }

        // ---- S^T = K @ Q^T : st[mt] rows kv = mt*16 + l4*4 + r, cols q = l15 ----
        f32x4 st[4];
        #pragma unroll
        for (int mt = 0; mt < 4; ++mt) st[mt] = (f32x4){0.f, 0.f, 0.f, 0.f};
        #pragma unroll
        for (int mt = 0; mt < 4; ++mt) {
            #pragma unroll
            for (int kc = 0; kc < 4; ++kc) {
                s16x8 kf = *(const s16x8*)((const char*)Klds[cur] +
                            (mt * 16 + l15) * 256 + (((kc * 4 + l4) * 16) ^ xv));
                st[mt] = MFMA16(kf, qf[kc], st[mt]);
            }
        }

        // ---- mask apply ----
        #pragma unroll
        for (int mt = 0; mt < 4; ++mt)
            #pragma unroll
            for (int r = 0; r < 4; ++r)
                st[mt][r] = fmaf(mk[mt][r], st[mt][r] + 10000.f, -10000.f);

        // ---- in-register softmax over kv ----
        float x0 = fmaxf(fmaxf(st[0][0], st[0][1]), fmaxf(st[0][2], st[0][3]));
        float x1 = fmaxf(fmaxf(st[1][0], st[1][1]), fmaxf(st[1][2], st[1][3]));
        float x2 = fmaxf(fmaxf(st[2][0], st[2][1]), fmaxf(st[2][2], st[2][3]));
        float x3 = fmaxf(fmaxf(st[3][0], st[3][1]), fmaxf(st[3][2], st[3][3]));
        float rm = fmaxf(fmaxf(x0, x1), fmaxf(x2, x3));
        rm = fmaxf(rm, __shfl_xor(rm, 16));
        rm = fmaxf(rm, __shfl_xor(rm, 32));

        if (!__all(rm <= mrun + 8.f)) {       // defer-max
            float nm = fmaxf(mrun, rm);
            float al = __expf(mrun - nm);
            mrun = nm;
            lrun *= al;
            float alr0 = __shfl(al, l4 * 4 + 0);
            float alr1 = __shfl(al, l4 * 4 + 1);
            float alr2 = __shfl(al, l4 * 4 + 2);
            float alr3 = __shfl(al, l4 * 4 + 3);
            #pragma unroll
            for (int nn = 0; nn < 8; ++nn) {
                acc[nn][0] *= alr0; acc[nn][1] *= alr1;
                acc[nn][2] *= alr2; acc[nn][3] *= alr3;
            }
        }

        float rs = 0.f;
        #pragma unroll
        for (int mt = 0; mt < 4; ++mt) {
            #pragma unroll
            for (int r = 0; r < 4; ++r) {
                float pe = __expf(st[mt][r] - mrun);
                st[mt][r] = pe;
                rs += pe;
            }
        }
        rs += __shfl_xor(rs, 16);
        rs += __shfl_xor(rs, 32);
        lrun += rs;

        // ---- pack P^T to bf16 ----
        union PK { int d[2]; __bf16 hh[4]; };
        PK pk0, pk1, pk2, pk3;
        pk0.hh[0]=(__bf16)st[0][0]; pk0.hh[1]=(__bf16)st[0][1]; pk0.hh[2]=(__bf16)st[0][2]; pk0.hh[3]=(__bf16)st[0][3];
        pk1.hh[0]=(__bf16)st[1][0]; pk1.hh[1]=(__bf16)st[1][1]; pk1.hh[2]=(__bf16)st[1][2]; pk1.hh[3]=(__bf16)st[1][3];
        pk2.hh[0]=(__bf16)st[2][0]; pk2.hh[1]=(__bf16)st[2][1]; pk2.hh[2]=(__bf16)st[2][2]; pk2.hh[3]=(__bf16)st[2][3];
        pk3.hh[0]=(__bf16)st[3][0]; pk3.hh[1]=(__bf16)st[3][1]; pk3.hh[2]=(__bf16)st[3][2]; pk3.hh[3]=(__bf16)st[3][3];

        // ---- assemble PV A-fragments via shuffles ----
        const int srcA = (l4 & 1) * 32 + l15;
        const int srcB = srcA + 16;
        const int sel  = l4 >> 1;
        s16x8 pa[2];
        {
            union { int d[4]; s16x8 v; } ua;
            int a00 = __shfl(pk0.d[0], srcA), a10 = __shfl(pk1.d[0], srcA);
            int a01 = __shfl(pk0.d[1], srcA), a11 = __shfl(pk1.d[1], srcA);
            int b00 = __shfl(pk0.d[0], srcB), b10 = __shfl(pk1.d[0], srcB);
            int b01 = __shfl(pk0.d[1], srcB), b11 = __shfl(pk1.d[1], srcB);
            ua.d[0] = sel ? a10 : a00; ua.d[1] = sel ? a11 : a01;
            ua.d[2] = sel ? b10 : b00; ua.d[3] = sel ? b11 : b01;
            pa[0] = ua.v;
        }
        {
            union { int d[4]; s16x8 v; } ua;
            int a00 = __shfl(pk2.d[0], srcA), a10 = __shfl(pk3.d[0], srcA);
            int a01 = __shfl(pk2.d[1], srcA), a11 = __shfl(pk3.d[1], srcA);
            int b00 = __shfl(pk2.d[0], srcB), b10 = __shfl(pk3.d[0], srcB);
            int b01 = __shfl(pk2.d[1], srcB), b11 = __shfl(pk3.d[1], srcB);
            ua.d[0] = sel ? a10 : a00; ua.d[1] = sel ? a11 : a01;
            ua.d[2] = sel ? b10 : b00; ua.d[3] = sel ? b11 : b01;
            pa[1] = ua.v;
        }

        // ---- O += P @ V ----
        #pragma unroll
        for (int nn = 0; nn < 8; ++nn) {
            s16x8 vf0 = *(const s16x8*)((const char*)Vt[cur] +
                          (nn * 16 + l15) * 128 + ((l4 * 16) ^ xv));
            s16x8 vf1 = *(const s16x8*)((const char*)Vt[cur] +
                          (nn * 16 + l15) * 128 + ((64 + l4 * 16) ^ xv));
            acc[nn] = MFMA16(pa[0], vf0, acc[nn]);
            acc[nn] = MFMA16(pa[1], vf1, acc[nn]);
        }

        // ---- stage WRITES for tile tn into buf cur^1 (vmcnt waits land here) ----
        {
            int row0 = krow;
            int byte0 = row0 * 256 + ((kcg * 16) ^ ((row0 & 7) << 4));
            *(s16x8*)((char*)Klds[cur ^ 1] + byte0) = cvt8(ka0, kb0);
            int row1 = krow + 32;
            int byte1 = row1 * 256 + ((kcg * 16) ^ ((row1 & 7) << 4));
            *(s16x8*)((char*)Klds[cur ^ 1] + byte1) = cvt8(ka1, kb1);

            union { s16x8 v; __bf16 hh[8]; } u0, u1;
            #pragma unroll
            for (int j = 0; j < 8; ++j) u0.hh[j] = (__bf16)vp0[j];
            int vb0 = vhd * 128 + (((vkvb) * 16) ^ ((vhd & 7) << 4));
            *(s16x8*)((char*)Vt[cur ^ 1] + vb0) = u0.v;
            #pragma unroll
            for (int j = 0; j < 8; ++j) u1.hh[j] = (__bf16)vp1[j];
            int vb1 = vhd * 128 + (((vkvb + 4) * 16) ^ ((vhd & 7) << 4));
            *(s16x8*)((char*)Vt[cur ^ 1] + vb1) = u1.v;
        }

        __syncthreads();   // one barrier per tile
    }

    // ---- epilogue ----
    float lr0 = __shfl(lrun, l4 * 4 + 0);
    float lr1 = __shfl(lrun, l4 * 4 + 1);
    float lr2 = __shfl(lrun, l4 * 4 + 2);
    float lr3 = __shfl(lrun, l4 * 4 + 3);
    float inv0 = 1.f / lr0, inv1 = 1.f / lr1, inv2 = 1.f / lr2, inv3 = 1.f / lr3;
    float* obase = ctx + (((size_t)(b * NH_ + h)) * SQ_ + q0 + w * 16 + l4 * 4) * HD_ + l15;
    #pragma unroll
    for (int nn = 0; nn < 8; ++nn) {
        obase[(size_t)0 * HD_ + nn * 16] = acc[nn][0] * inv0;
        obase[(size_t)1 * HD_ + nn * 16] = acc[nn][1] * inv1;
        obase[(size_t)2 * HD_ + nn * 16] = acc[nn][2] * inv2;
        obase[(size_t)3 * HD_ + nn * 16] = acc[nn][3] * inv3;
    }
}

// cache_kv: out[b][s][part][h][d] = (part ? v : k)[b][h][s][d]
__global__ void cachekv_kernel(const float* __restrict__ k, const float* __restrict__ v,
                               float* __restrict__ out)
{
    size_t i = ((size_t)blockIdx.x * 256 + threadIdx.x) * 4;
    unsigned f = (unsigned)i;
    unsigned d    = f & 127;
    unsigned hh   = (f >> 7) & 31;
    unsigned part = (f >> 12) & 1;
    unsigned s    = (f >> 13) & 511;
    unsigned bb   = f >> 22;
    const float* src = (part ? v : k) + (((size_t)(bb * 32u + hh)) * 512u + s) * 128u + d;
    *(float4*)(out + i) = *(const float4*)src;
}

extern "C" void kernel_launch(void* const* d_in, const int* in_sizes, int n_in,
                              void* d_out, int out_size, void* d_ws, size_t ws_size,
                              hipStream_t stream) {
    const float* q    = (const float*)d_in[0];
    const float* k    = (const float*)d_in[1];
    const float* v    = (const float*)d_in[2];
    const float* mask = (const float*)d_in[3];
    const float* mem  = (const float*)d_in[4];
    float* out = (float*)d_out;

    attn_kernel<<<dim3(B_ * NH_ * (SQ_ / QB_)), dim3(512), 0, stream>>>(q, k, v, mask, mem, out);

    const int ctx_elems = B_ * NH_ * SQ_ * HD_;                 // 8388608
    const int ckv_elems = B_ * SQ_ * 2 * NH_ * HD_;             // 16777216
    cachekv_kernel<<<dim3(ckv_elems / 4 / 256), dim3(256), 0, stream>>>(k, v, out + ctx_elems);
    (void)in_sizes; (void)n_in; (void)out_size; (void)d_ws; (void)ws_size;
}